// Round 1
// 551.441 us; speedup vs baseline: 1.1029x; 1.1029x over previous
//
#include <hip/hip_runtime.h>
#include <hip/hip_bf16.h>
#include <stdint.h>

// Problem constants
#define T_TOK 8192
#define DIM 4096
#define ODIM 4096
#define NL 8
#define RANK 16
#define KAUG 4224   // DIM + NL*RANK
#define NKT (KAUG / 64)   // 66 K-tiles

// ---------- helpers ----------
__device__ __forceinline__ uint16_t f2b(float x) {
    uint32_t u = __builtin_bit_cast(uint32_t, x);
    u += 0x7fffu + ((u >> 16) & 1u);   // RNE
    return (uint16_t)(u >> 16);
}

typedef __attribute__((ext_vector_type(4))) float floatx4;
typedef __attribute__((ext_vector_type(8))) __bf16 bf16x8;

__device__ __forceinline__ void load_lds16(const uint16_t* g, uint16_t* l) {
    __builtin_amdgcn_global_load_lds(
        (const __attribute__((address_space(1))) uint32_t*)g,
        (__attribute__((address_space(3))) uint32_t*)l, 16, 0, 0);
}

// ---------- kernel 1: fused pack of all bf16 operands (unchanged) ----------
__global__ __launch_bounds__(256) void pack_all(const float* __restrict__ x,
                                                const float* __restrict__ W,
                                                const float* __restrict__ la,
                                                const float* __restrict__ lb,
                                                uint16_t* __restrict__ xaug,
                                                uint16_t* __restrict__ waug,
                                                uint16_t* __restrict__ aall) {
    int b = blockIdx.x;
    int tid = threadIdx.x;
    const float* src;
    uint16_t* dst;
    if (b < ODIM)               { src = W  + (size_t)b * DIM;                 dst = waug + (size_t)b * KAUG; }
    else if (b < ODIM + T_TOK)  { int t = b - ODIM;
                                  src = x  + (size_t)t * DIM;                 dst = xaug + (size_t)t * KAUG; }
    else                        { int r = b - ODIM - T_TOK;
                                  src = la + (size_t)r * DIM;                 dst = aall + (size_t)r * DIM; }
#pragma unroll
    for (int k = 0; k < 4; ++k) {
        int i4 = k * 256 + tid;
        float4 v = ((const float4*)src)[i4];
        ushort4 bv;
        bv.x = f2b(v.x); bv.y = f2b(v.y); bv.z = f2b(v.z); bv.w = f2b(v.w);
        *(ushort4*)(dst + (size_t)i4 * 4) = bv;
    }
    if (b < ODIM && tid < NL * RANK) {
        int l = tid >> 4, r = tid & 15;
        dst[DIM + tid] = f2b(lb[((size_t)l * ODIM + b) * RANK + r]);
    }
}

// ---------- kernel 2: MFMA shrink (unchanged) ----------
#define SBM 32
__global__ __launch_bounds__(256) void shrink_gemm(const uint16_t* __restrict__ xa,
                                                   const uint16_t* __restrict__ aall,
                                                   const int* __restrict__ idx,
                                                   uint16_t* __restrict__ xaug) {
    __shared__ uint16_t sA[SBM * 64];   // 4 KB
    __shared__ uint16_t sB[128 * 64];   // 16 KB
    int tid = threadIdx.x, lane = tid & 63, wid = tid >> 6;
    int bm = blockIdx.x;
    int q = lane >> 4, r16 = lane & 15;

    int rS = tid >> 3;
    int kcS = (tid & 7) ^ (rS & 7);
    const uint16_t* gA = xa + (size_t)(bm * SBM + rS) * KAUG + kcS * 8;
    const uint16_t* gB0 = aall + (size_t)(rS) * DIM + kcS * 8;
    const uint16_t* gB1 = aall + (size_t)(32 + rS) * DIM + kcS * 8;
    const uint16_t* gB2 = aall + (size_t)(64 + rS) * DIM + kcS * 8;
    const uint16_t* gB3 = aall + (size_t)(96 + rS) * DIM + kcS * 8;
    uint16_t* lA  = sA + wid * 512;
    uint16_t* lB0 = sB + wid * 512;
    uint16_t* lB1 = sB + 2048 + wid * 512;
    uint16_t* lB2 = sB + 4096 + wid * 512;
    uint16_t* lB3 = sB + 6144 + wid * 512;

    int sw0 = (q ^ (r16 & 7)) * 8;
    int sw1 = ((4 + q) ^ (r16 & 7)) * 8;

    floatx4 acc[2][2];
#pragma unroll
    for (int i = 0; i < 2; ++i)
#pragma unroll
        for (int j = 0; j < 2; ++j) acc[i][j] = (floatx4){0.f, 0.f, 0.f, 0.f};

    for (int k0 = 0; k0 < DIM; k0 += 64) {
        __syncthreads();
        load_lds16(gA + k0, lA);
        load_lds16(gB0 + k0, lB0);
        load_lds16(gB1 + k0, lB1);
        load_lds16(gB2 + k0, lB2);
        load_lds16(gB3 + k0, lB3);
        __syncthreads();
#pragma unroll
        for (int kk = 0; kk < 2; ++kk) {
            int sw = kk ? sw1 : sw0;
            bf16x8 af[2], bv[2];
#pragma unroll
            for (int i = 0; i < 2; ++i)
                af[i] = *(const bf16x8*)(sA + (i * 16 + r16) * 64 + sw);
#pragma unroll
            for (int j = 0; j < 2; ++j)
                bv[j] = *(const bf16x8*)(sB + (wid * 32 + j * 16 + r16) * 64 + sw);
#pragma unroll
            for (int i = 0; i < 2; ++i)
#pragma unroll
                for (int j = 0; j < 2; ++j)
                    acc[i][j] = __builtin_amdgcn_mfma_f32_16x16x32_bf16(af[i], bv[j], acc[i][j], 0, 0, 0);
        }
    }
#pragma unroll
    for (int i = 0; i < 2; ++i) {
#pragma unroll
        for (int j = 0; j < 2; ++j) {
            int p = wid * 32 + j * 16 + r16;
            int lp = p >> 4;
#pragma unroll
            for (int e = 0; e < 4; ++e) {
                int t = bm * SBM + i * 16 + q * 4 + e;
                uint16_t v = (idx[t] == lp) ? f2b(acc[i][j][e]) : (uint16_t)0;
                xaug[(size_t)t * KAUG + DIM + p] = v;
            }
        }
    }
}

// ---------- kernel 3: 256x256 8-phase bf16 NT GEMM (T1+T2+T3+T4+T5) ----------
// 512 threads = 8 waves (2M x 4N); per-wave output 128x64; BK=64; 128 KiB LDS dbuf.
// Counted vmcnt(6) at phases 4/8 keeps 3 half-tiles in flight across raw s_barriers.
#define GBM 256
#define GBN 256

__global__ __launch_bounds__(512) void gemm_aug8(const uint16_t* __restrict__ A,
                                                 const uint16_t* __restrict__ B,
                                                 float* __restrict__ C) {
    __shared__ uint16_t sA[2][GBM * 64];   // 2 x 32 KB
    __shared__ uint16_t sB[2][GBN * 64];   // 2 x 32 KB

    int tid = threadIdx.x;
    int lane = tid & 63, wid = tid >> 6;
    int q = lane >> 4, r16 = lane & 15;
    int wm = (wid >> 2) * 128;             // wave M offset (0/128)
    int wn = (wid & 3) * 64;               // wave N offset (0..192)

    // XCD-aware bijective swizzle: grid = 512 = 16(bn) x 32(bm), 512 % 8 == 0
    int cpx = gridDim.x >> 3;
    int wgid = (blockIdx.x & 7) * cpx + (blockIdx.x >> 3);
    int bn = wgid & 15;
    int bm = wgid >> 4;

    // --- staging addressing: linear LDS dest + chunk-XOR pre-swizzled global src ---
    int rS = tid >> 3;                     // 0..63 (row within 64-row load)
    int cS = (tid & 7) ^ (rS & 7);         // swizzled 16B chunk in global
    const uint16_t* gA0 = A + (size_t)(bm * GBM + rS) * KAUG + cS * 8;
    const uint16_t* gB0 = B + (size_t)(bn * GBN + rS) * KAUG + cS * 8;
    int ldsOff = wid * 512;                // wave-uniform linear dest (8 rows * 64 el)

    auto stageA = [&](int bufi, int half, int tk) {
        const uint16_t* g = gA0 + (size_t)(half * 128) * KAUG + (size_t)tk * 64;
        uint16_t* l = &sA[bufi][half * 8192 + ldsOff];
        load_lds16(g, l);
        load_lds16(g + (size_t)64 * KAUG, l + 4096);
    };
    auto stageB = [&](int bufi, int half, int tk) {
        const uint16_t* g = gB0 + (size_t)(half * 128) * KAUG + (size_t)tk * 64;
        uint16_t* l = &sB[bufi][half * 8192 + ldsOff];
        load_lds16(g, l);
        load_lds16(g + (size_t)64 * KAUG, l + 4096);
    };

    // --- fragment reads (same conflict-free XOR pattern as staging) ---
    int swz[2] = { ((0 + q) ^ (r16 & 7)) * 8, ((4 + q) ^ (r16 & 7)) * 8 };

    bf16x8 aH[4][2];   // current A half: 4 m-frags x 2 kk
    bf16x8 bfv[4][2];  // full B: 4 n-frags x 2 kk
    floatx4 acc[8][4];
#pragma unroll
    for (int i = 0; i < 8; ++i)
#pragma unroll
        for (int j = 0; j < 4; ++j) acc[i][j] = (floatx4){0.f, 0.f, 0.f, 0.f};

    auto rdA = [&](int b, int mh) {
#pragma unroll
        for (int mf = 0; mf < 4; ++mf)
#pragma unroll
            for (int kk = 0; kk < 2; ++kk)
                aH[mf][kk] = *(const bf16x8*)&sA[b][(wm + mh * 64 + mf * 16 + r16) * 64 + swz[kk]];
    };
    auto rdB = [&](int b) {
#pragma unroll
        for (int nf = 0; nf < 4; ++nf)
#pragma unroll
            for (int kk = 0; kk < 2; ++kk)
                bfv[nf][kk] = *(const bf16x8*)&sB[b][(wn + nf * 16 + r16) * 64 + swz[kk]];
    };
    auto mmaQ = [&](int mh, int nh) {   // 16 MFMA: quadrant (4 m-frags x 2 n-frags) x 2 kk
        __builtin_amdgcn_s_setprio(1);
#pragma unroll
        for (int mf = 0; mf < 4; ++mf)
#pragma unroll
            for (int nf = 0; nf < 2; ++nf)
#pragma unroll
                for (int kk = 0; kk < 2; ++kk)
                    acc[mh * 4 + mf][nh * 2 + nf] = __builtin_amdgcn_mfma_f32_16x16x32_bf16(
                        aH[mf][kk], bfv[nh * 2 + nf][kk], acc[mh * 4 + mf][nh * 2 + nf], 0, 0, 0);
        __builtin_amdgcn_s_setprio(0);
    };

#define BAR  __builtin_amdgcn_s_barrier()
#define LGK0 { asm volatile("s_waitcnt lgkmcnt(0)" ::: "memory"); __builtin_amdgcn_sched_barrier(0); }
#define VM6  asm volatile("s_waitcnt vmcnt(6)" ::: "memory")
#define VM0  asm volatile("s_waitcnt vmcnt(0)" ::: "memory")

    // --- prologue: tile0 fully + tile1 {Btop,Bbot,Atop}; vmcnt(6) lands tile0 ---
    stageB(0, 0, 0); stageB(0, 1, 0); stageA(0, 0, 0); stageA(0, 1, 0);
    stageB(1, 0, 1); stageB(1, 1, 1); stageA(1, 0, 1);
    VM6;
    BAR;

#pragma unroll 1
    for (int i = 0; i < NKT / 2; ++i) {
        int t1 = 2 * i + 1, t2 = 2 * i + 2, t3 = 2 * i + 3;
        // ---- tile 2i from buf0 ----
        // P1: read B-full + A[mh0]; stage t1.Abot -> buf1 (buf1.A free since prev P7)
        rdB(0); rdA(0, 0);
        stageA(1, 1, t1);
        BAR; LGK0; mmaQ(0, 0); BAR;
        // P2: stage t2.Btop -> buf0 (buf0.B read done at P1)
        if (t2 < NKT) stageB(0, 0, t2);
        BAR; mmaQ(0, 1); BAR;
        // P3: read A[mh1]; stage t2.Bbot
        rdA(0, 1);
        if (t2 < NKT) stageB(0, 1, t2);
        BAR; LGK0; mmaQ(1, 0); BAR;
        // P4: stage t2.Atop (buf0.A read done at P3); counted wait lands tile t1
        if (t2 < NKT) { stageA(0, 0, t2); VM6; } else { VM0; }
        BAR; mmaQ(1, 1); BAR;
        // ---- tile 2i+1 from buf1 ----
        // P5: read B-full + A[mh0] from buf1; stage t2.Abot
        rdB(1); rdA(1, 0);
        if (t2 < NKT) stageA(0, 1, t2);
        BAR; LGK0; mmaQ(0, 0); BAR;
        // P6: stage t3.Btop -> buf1 (buf1.B read done at P5)
        if (t3 < NKT) stageB(1, 0, t3);
        BAR; mmaQ(0, 1); BAR;
        // P7: read A[mh1]; stage t3.Bbot
        rdA(1, 1);
        if (t3 < NKT) stageB(1, 1, t3);
        BAR; LGK0; mmaQ(1, 0); BAR;
        // P8: stage t3.Atop (buf1.A read done at P7); counted wait lands tile t2
        if (t3 < NKT) { stageA(1, 0, t3); VM6; } else { VM0; }
        BAR; mmaQ(1, 1); BAR;
    }

    // --- epilogue: C/D mapping col = lane&15, row = (lane>>4)*4 + reg ---
#pragma unroll
    for (int mf = 0; mf < 8; ++mf) {
#pragma unroll
        for (int nf = 0; nf < 4; ++nf) {
            int col = bn * GBN + wn + nf * 16 + r16;
            int rowb = bm * GBM + wm + mf * 16 + q * 4;
#pragma unroll
            for (int e = 0; e < 4; ++e)
                C[(size_t)(rowb + e) * ODIM + col] = acc[mf][nf][e];
        }
    }
#undef BAR
#undef LGK0
#undef VM6
#undef VM0
}

// ---------- launcher ----------
extern "C" void kernel_launch(void* const* d_in, const int* in_sizes, int n_in,
                              void* d_out, int out_size, void* d_ws, size_t ws_size,
                              hipStream_t stream) {
    const float* x  = (const float*)d_in[0];
    const float* W  = (const float*)d_in[1];
    const float* la = (const float*)d_in[2];
    const float* lb = (const float*)d_in[3];
    const int* idx  = (const int*)d_in[4];
    float* out = (float*)d_out;

    uint16_t* xaug = (uint16_t*)d_ws;                         // [8192][4224] bf16
    uint16_t* waug = xaug + (size_t)T_TOK * KAUG;             // [4096][4224] bf16
    uint16_t* aall = waug + (size_t)ODIM * KAUG;              // [128][4096]  bf16

    hipLaunchKernelGGL(pack_all, dim3(ODIM + T_TOK + NL * RANK), dim3(256), 0, stream,
                       x, W, la, lb, xaug, waug, aall);
    hipLaunchKernelGGL(shrink_gemm, dim3(T_TOK / SBM), dim3(256), 0, stream,
                       xaug, aall, idx, xaug);
    hipLaunchKernelGGL(gemm_aug8, dim3((T_TOK / GBM) * (ODIM / GBN)), dim3(512), 0, stream,
                       xaug, waug, out);
}

// Round 2
// 551.267 us; speedup vs baseline: 1.1032x; 1.0003x over previous
//
#include <hip/hip_runtime.h>
#include <hip/hip_bf16.h>
#include <stdint.h>

// Problem constants
#define T_TOK 8192
#define DIM 4096
#define ODIM 4096
#define NL 8
#define RANK 16
#define KAUG 4224   // DIM + NL*RANK
#define NKT (KAUG / 64)   // 66 K-tiles

// ---------- helpers ----------
__device__ __forceinline__ uint16_t f2b(float x) {
    uint32_t u = __builtin_bit_cast(uint32_t, x);
    u += 0x7fffu + ((u >> 16) & 1u);   // RNE
    return (uint16_t)(u >> 16);
}

typedef __attribute__((ext_vector_type(4))) float floatx4;
typedef __attribute__((ext_vector_type(8))) __bf16 bf16x8;

__device__ __forceinline__ void load_lds16(const uint16_t* g, uint16_t* l) {
    __builtin_amdgcn_global_load_lds(
        (const __attribute__((address_space(1))) uint32_t*)g,
        (__attribute__((address_space(3))) uint32_t*)l, 16, 0, 0);
}

// ---------- kernel 1: fused pack of all bf16 operands (unchanged) ----------
__global__ __launch_bounds__(256) void pack_all(const float* __restrict__ x,
                                                const float* __restrict__ W,
                                                const float* __restrict__ la,
                                                const float* __restrict__ lb,
                                                uint16_t* __restrict__ xaug,
                                                uint16_t* __restrict__ waug,
                                                uint16_t* __restrict__ aall) {
    int b = blockIdx.x;
    int tid = threadIdx.x;
    const float* src;
    uint16_t* dst;
    if (b < ODIM)               { src = W  + (size_t)b * DIM;                 dst = waug + (size_t)b * KAUG; }
    else if (b < ODIM + T_TOK)  { int t = b - ODIM;
                                  src = x  + (size_t)t * DIM;                 dst = xaug + (size_t)t * KAUG; }
    else                        { int r = b - ODIM - T_TOK;
                                  src = la + (size_t)r * DIM;                 dst = aall + (size_t)r * DIM; }
#pragma unroll
    for (int k = 0; k < 4; ++k) {
        int i4 = k * 256 + tid;
        float4 v = ((const float4*)src)[i4];
        ushort4 bv;
        bv.x = f2b(v.x); bv.y = f2b(v.y); bv.z = f2b(v.z); bv.w = f2b(v.w);
        *(ushort4*)(dst + (size_t)i4 * 4) = bv;
    }
    if (b < ODIM && tid < NL * RANK) {
        int l = tid >> 4, r = tid & 15;
        dst[DIM + tid] = f2b(lb[((size_t)l * ODIM + b) * RANK + r]);
    }
}

// ---------- kernel 2: MFMA shrink (unchanged) ----------
#define SBM 32
__global__ __launch_bounds__(256) void shrink_gemm(const uint16_t* __restrict__ xa,
                                                   const uint16_t* __restrict__ aall,
                                                   const int* __restrict__ idx,
                                                   uint16_t* __restrict__ xaug) {
    __shared__ uint16_t sA[SBM * 64];   // 4 KB
    __shared__ uint16_t sB[128 * 64];   // 16 KB
    int tid = threadIdx.x, lane = tid & 63, wid = tid >> 6;
    int bm = blockIdx.x;
    int q = lane >> 4, r16 = lane & 15;

    int rS = tid >> 3;
    int kcS = (tid & 7) ^ (rS & 7);
    const uint16_t* gA = xa + (size_t)(bm * SBM + rS) * KAUG + kcS * 8;
    const uint16_t* gB0 = aall + (size_t)(rS) * DIM + kcS * 8;
    const uint16_t* gB1 = aall + (size_t)(32 + rS) * DIM + kcS * 8;
    const uint16_t* gB2 = aall + (size_t)(64 + rS) * DIM + kcS * 8;
    const uint16_t* gB3 = aall + (size_t)(96 + rS) * DIM + kcS * 8;
    uint16_t* lA  = sA + wid * 512;
    uint16_t* lB0 = sB + wid * 512;
    uint16_t* lB1 = sB + 2048 + wid * 512;
    uint16_t* lB2 = sB + 4096 + wid * 512;
    uint16_t* lB3 = sB + 6144 + wid * 512;

    int sw0 = (q ^ (r16 & 7)) * 8;
    int sw1 = ((4 + q) ^ (r16 & 7)) * 8;

    floatx4 acc[2][2];
#pragma unroll
    for (int i = 0; i < 2; ++i)
#pragma unroll
        for (int j = 0; j < 2; ++j) acc[i][j] = (floatx4){0.f, 0.f, 0.f, 0.f};

    for (int k0 = 0; k0 < DIM; k0 += 64) {
        __syncthreads();
        load_lds16(gA + k0, lA);
        load_lds16(gB0 + k0, lB0);
        load_lds16(gB1 + k0, lB1);
        load_lds16(gB2 + k0, lB2);
        load_lds16(gB3 + k0, lB3);
        __syncthreads();
#pragma unroll
        for (int kk = 0; kk < 2; ++kk) {
            int sw = kk ? sw1 : sw0;
            bf16x8 af[2], bv[2];
#pragma unroll
            for (int i = 0; i < 2; ++i)
                af[i] = *(const bf16x8*)(sA + (i * 16 + r16) * 64 + sw);
#pragma unroll
            for (int j = 0; j < 2; ++j)
                bv[j] = *(const bf16x8*)(sB + (wid * 32 + j * 16 + r16) * 64 + sw);
#pragma unroll
            for (int i = 0; i < 2; ++i)
#pragma unroll
                for (int j = 0; j < 2; ++j)
                    acc[i][j] = __builtin_amdgcn_mfma_f32_16x16x32_bf16(af[i], bv[j], acc[i][j], 0, 0, 0);
        }
    }
#pragma unroll
    for (int i = 0; i < 2; ++i) {
#pragma unroll
        for (int j = 0; j < 2; ++j) {
            int p = wid * 32 + j * 16 + r16;
            int lp = p >> 4;
#pragma unroll
            for (int e = 0; e < 4; ++e) {
                int t = bm * SBM + i * 16 + q * 4 + e;
                uint16_t v = (idx[t] == lp) ? f2b(acc[i][j][e]) : (uint16_t)0;
                xaug[(size_t)t * KAUG + DIM + p] = v;
            }
        }
    }
}

// ---------- kernel 3: 256x256 single-barrier 8-phase bf16 NT GEMM ----------
// 512 threads = 8 waves (2M x 4N). Phase = {[vmcnt(N)]; s_barrier; ds_reads;
// stage; setprio-MFMA}. No explicit lgkmcnt (compiler emits counted waits) ->
// inter-wave LDS/MFMA overlap. Reads balanced 12/4/8/0 per tile; each phase's
// reads feed exactly its own MFMA quadrant.
// A stage parts: part0 ("early") = row chunks {0-63,128-191} (read by mmaQ(0,*)),
// part1 ("late") = {64-127,192-255} (read by mmaQ(1,*)).
#define GBM 256
#define GBN 256

__global__ __launch_bounds__(512) void gemm_aug8(const uint16_t* __restrict__ A,
                                                 const uint16_t* __restrict__ B,
                                                 float* __restrict__ C) {
    __shared__ uint16_t sA[2][GBM * 64];   // 2 x 32 KB
    __shared__ uint16_t sB[2][GBN * 64];   // 2 x 32 KB

    int tid = threadIdx.x;
    int lane = tid & 63, wid = tid >> 6;
    int q = lane >> 4, r16 = lane & 15;
    int wm = (wid >> 2) * 128;             // wave M offset (0/128)
    int wn = (wid & 3) * 64;               // wave N offset (0..192)

    // XCD-aware bijective swizzle: grid = 512 = 16(bn) x 32(bm), 512 % 8 == 0
    int cpx = gridDim.x >> 3;
    int wgid = (blockIdx.x & 7) * cpx + (blockIdx.x >> 3);
    int bn = wgid & 15;
    int bm = wgid >> 4;

    // staging addressing: linear LDS dest + chunk-XOR pre-swizzled global src
    int rS = tid >> 3;                     // 0..63 (row within a 64-row chunk)
    int cS = (tid & 7) ^ (rS & 7);         // swizzled 16B chunk in global
    const uint16_t* gA0 = A + (size_t)(bm * GBM + rS) * KAUG + cS * 8;
    const uint16_t* gB0 = B + (size_t)(bn * GBN + rS) * KAUG + cS * 8;
    int ldsOff = wid * 512;                // wave-uniform linear dest (8 rows * 64 el)

    // A: part 0 -> chunks {0,2}; part 1 -> chunks {1,3}
    auto stageA2 = [&](int bufi, int part, int tk) {
        const uint16_t* g = gA0 + (size_t)tk * 64;
        uint16_t* l = &sA[bufi][ldsOff];
        load_lds16(g + (size_t)(part * 64) * KAUG,       l + part * 4096);
        load_lds16(g + (size_t)((part + 2) * 64) * KAUG, l + (part + 2) * 4096);
    };
    // B: half 0 -> chunks {0,1} (rows 0-127); half 1 -> chunks {2,3}
    auto stageBh = [&](int bufi, int half, int tk) {
        const uint16_t* g = gB0 + (size_t)(half * 128) * KAUG + (size_t)tk * 64;
        uint16_t* l = &sB[bufi][half * 8192 + ldsOff];
        load_lds16(g, l);
        load_lds16(g + (size_t)64 * KAUG, l + 4096);
    };

    int swz[2] = { ((0 + q) ^ (r16 & 7)) * 8, ((4 + q) ^ (r16 & 7)) * 8 };

    bf16x8 aH[4][2];   // current A half: 4 m-frags x 2 kk
    bf16x8 bfv[4][2];  // full B: 4 n-frags x 2 kk
    floatx4 acc[8][4];
#pragma unroll
    for (int i = 0; i < 8; ++i)
#pragma unroll
        for (int j = 0; j < 4; ++j) acc[i][j] = (floatx4){0.f, 0.f, 0.f, 0.f};

    auto rdA = [&](int b, int mh) {        // 8 x ds_read_b128
#pragma unroll
        for (int mf = 0; mf < 4; ++mf)
#pragma unroll
            for (int kk = 0; kk < 2; ++kk)
                aH[mf][kk] = *(const bf16x8*)&sA[b][(wm + mh * 64 + mf * 16 + r16) * 64 + swz[kk]];
    };
    auto rdBq = [&](int b, int nh) {       // 4 x ds_read_b128 (one n-quarter pair)
#pragma unroll
        for (int nf = 0; nf < 2; ++nf)
#pragma unroll
            for (int kk = 0; kk < 2; ++kk)
                bfv[nh * 2 + nf][kk] = *(const bf16x8*)&sB[b][(wn + (nh * 2 + nf) * 16 + r16) * 64 + swz[kk]];
    };
    auto mmaQ = [&](int mh, int nh) {      // 16 MFMA: one C-quadrant x K=64
        __builtin_amdgcn_s_setprio(1);
#pragma unroll
        for (int mf = 0; mf < 4; ++mf)
#pragma unroll
            for (int nf = 0; nf < 2; ++nf)
#pragma unroll
                for (int kk = 0; kk < 2; ++kk)
                    acc[mh * 4 + mf][nh * 2 + nf] = __builtin_amdgcn_mfma_f32_16x16x32_bf16(
                        aH[mf][kk], bfv[nh * 2 + nf][kk], acc[mh * 4 + mf][nh * 2 + nf], 0, 0, 0);
        __builtin_amdgcn_s_setprio(0);
    };

#define BAR  __builtin_amdgcn_s_barrier()
#define VM6  asm volatile("s_waitcnt vmcnt(6)" ::: "memory")
#define VM8  asm volatile("s_waitcnt vmcnt(8)" ::: "memory")
#define VM0  asm volatile("s_waitcnt vmcnt(0)" ::: "memory")

    // prologue: seed pipeline exactly like steady-state "prev P3..P8"
    // issue order: Aearly(t0), Btop(t0), Bbot(t0), Alate(t0), Aearly(t1), Btop(t1)
    stageA2(0, 0, 0); stageBh(0, 0, 0); stageBh(0, 1, 0); stageA2(0, 1, 0);
    stageA2(1, 0, 1); stageBh(1, 0, 1);

#pragma unroll 1
    for (int i = 0; i < NKT / 2; ++i) {
        int t1 = 2 * i + 1, t2 = 2 * i + 2, t3 = 2 * i + 3;
        bool full = (t2 < NKT);            // false only on the last iteration

        // ---- tile 2i from buf0 ----
        // P1: certifies buf0 {Aearly,Btop,Bbot} landed (issued >=6 loads ago)
        VM6; BAR;
        rdA(0, 0); rdBq(0, 0);
        stageBh(1, 1, t1);                 // buf1.Bbot(t1): buf1.B free since prev P6
        mmaQ(0, 0);
        // P2
        BAR;
        rdBq(0, 1);
        stageA2(1, 1, t1);                 // buf1.Alate(t1): free since prev P7
        mmaQ(0, 1);
        // P3: certifies buf0.Alate landed (8 loads in flight behind it)
        VM8; BAR;
        rdA(0, 1);
        if (full) stageA2(0, 0, t2);       // buf0.Aearly free since P1
        mmaQ(1, 0);
        // P4
        BAR;
        if (full) stageBh(0, 0, t2);       // buf0.B free since P2
        mmaQ(1, 1);

        // ---- tile 2i+1 from buf1 ----
        // P5: certifies buf1 {Btop(prev P8), Aearly(prev P7), Bbot(this P1)} landed
        if (full) { VM6; } else { VM0; }
        BAR;
        rdA(1, 0); rdBq(1, 0);
        if (full) stageBh(0, 1, t2);
        mmaQ(0, 0);
        // P6
        BAR;
        rdBq(1, 1);
        if (full) stageA2(0, 1, t2);
        mmaQ(0, 1);
        // P7: certifies buf1.Alate (staged this P2) landed
        if (full) { VM8; } else { VM0; }
        BAR;
        rdA(1, 1);
        if (t3 < NKT) stageA2(1, 0, t3);   // buf1.Aearly free since P5
        mmaQ(1, 0);
        // P8
        BAR;
        if (t3 < NKT) stageBh(1, 0, t3);   // buf1.B free since P6
        mmaQ(1, 1);
    }

    // epilogue: C/D mapping col = lane&15, row = (lane>>4)*4 + reg
#pragma unroll
    for (int mf = 0; mf < 8; ++mf) {
#pragma unroll
        for (int nf = 0; nf < 4; ++nf) {
            int col = bn * GBN + wn + nf * 16 + r16;
            int rowb = bm * GBM + wm + mf * 16 + q * 4;
#pragma unroll
            for (int e = 0; e < 4; ++e)
                C[(size_t)(rowb + e) * ODIM + col] = acc[mf][nf][e];
        }
    }
#undef BAR
#undef VM6
#undef VM8
#undef VM0
}

// ---------- launcher ----------
extern "C" void kernel_launch(void* const* d_in, const int* in_sizes, int n_in,
                              void* d_out, int out_size, void* d_ws, size_t ws_size,
                              hipStream_t stream) {
    const float* x  = (const float*)d_in[0];
    const float* W  = (const float*)d_in[1];
    const float* la = (const float*)d_in[2];
    const float* lb = (const float*)d_in[3];
    const int* idx  = (const int*)d_in[4];
    float* out = (float*)d_out;

    uint16_t* xaug = (uint16_t*)d_ws;                         // [8192][4224] bf16
    uint16_t* waug = xaug + (size_t)T_TOK * KAUG;             // [4096][4224] bf16
    uint16_t* aall = waug + (size_t)ODIM * KAUG;              // [128][4096]  bf16

    hipLaunchKernelGGL(pack_all, dim3(ODIM + T_TOK + NL * RANK), dim3(256), 0, stream,
                       x, W, la, lb, xaug, waug, aall);
    hipLaunchKernelGGL(shrink_gemm, dim3(T_TOK / SBM), dim3(256), 0, stream,
                       xaug, aall, idx, xaug);
    hipLaunchKernelGGL(gemm_aug8, dim3((T_TOK / GBM) * (ODIM / GBN)), dim3(512), 0, stream,
                       xaug, waug, out);
}